// Round 5
// baseline (2818.532 us; speedup 1.0000x reference)
//
#include <hip/hip_runtime.h>
#include <hip/hip_bf16.h>

#define TD 384
#define NHEAD 6
#define NFF 1536
#define NB 16
#define NTOK 481
#define NROWS (NB*NTOK)   // 7696
#define MPAD 7808         // 61*128

typedef __attribute__((ext_vector_type(8))) __bf16 bf16x8;
typedef __attribute__((ext_vector_type(4))) __bf16 bf16x4;
typedef __attribute__((ext_vector_type(4))) float f32x4;

static __device__ __forceinline__ float gelu_f(float v){
    return 0.5f*v*(1.0f + erff(v*0.70710678118654752f));
}

static __device__ __forceinline__ void gload16(const void* g, void* l){
    __builtin_amdgcn_global_load_lds((const __attribute__((address_space(1))) void*)g,
                                     (__attribute__((address_space(3))) void*)l, 16, 0, 0);
}

// stage ROWS x 64 bf16 tile (row-major, 128B rows) into linear LDS via global_load_lds,
// with XOR-swizzled SOURCE address so that a swizzled ds_read returns linear data (T2, rule 21).
template<int ROWS>
static __device__ __forceinline__ void stageT(const __bf16* g, int ldel, __bf16* lds, int w, int lane){
    #pragma unroll
    for (int j = 0; j < ROWS/32; ++j){
        int i = w*(ROWS/32) + j;
        int ol = i*1024 + lane*16;
        int row = ol >> 7, colb = ol & 127;
        int sc = colb ^ ((row & 7) << 4);
        gload16((const char*)g + (long)row*ldel*2 + sc, (char*)lds + i*1024);
    }
}

// ---------------- bf16 MFMA GEMM: C = scale*(A @ B^T) + bias [+gelu] [+R fp32] ----------------
// A: (M,K) bf16 row-major lda (rows padded to 128-multiples in-allocation);
// B: (N,K) bf16 ldb; C fp32 or bf16 (obf). K % 64 == 0.
// 256 thr = 4 waves (2x2); tile 128x128, each wave 64x64. Dbuf + counted vmcnt + XCD swizzle.
__global__ __launch_bounds__(256) void mgemm(
    const __bf16* __restrict__ A, int lda, long sA,
    const __bf16* __restrict__ Bm, int ldb, long sB,
    void* __restrict__ Cp, int ldc, long sC,
    const float* __restrict__ bias,
    const float* __restrict__ Rp, long sR,
    int M, int N, int K, float scale, int act, int obf)
{
    __shared__ __align__(16) __bf16 As[2][128*64];
    __shared__ __align__(16) __bf16 Bs[2][128*64];
    const int bz = blockIdx.z;
    A  += (long)bz*sA; Bm += (long)bz*sB;

    // bijective XCD-chunked swizzle (T1, m204)
    const int nwg = gridDim.x*gridDim.y;
    const int id  = blockIdx.y*gridDim.x + blockIdx.x;
    const int q8  = nwg >> 3, r8 = nwg & 7;
    const int xcd = id & 7, sub = id >> 3;
    const int nid = (xcd < r8 ? xcd*(q8+1) : r8*(q8+1) + (xcd-r8)*q8) + sub;
    const int m0 = (nid / gridDim.x) * 128, n0 = (nid % gridDim.x) * 128;

    const int tid = threadIdx.x;
    const int w = tid >> 6, lane = tid & 63;
    const int wr = w >> 1, wc = w & 1;
    const int lr = lane & 15, lg = lane >> 4;

    f32x4 acc[4][4];
    #pragma unroll
    for (int m=0;m<4;++m)
        #pragma unroll
        for (int n=0;n<4;++n)
            acc[m][n] = (f32x4){0.f,0.f,0.f,0.f};

    const __bf16* Ag = A + (long)m0*lda;
    const __bf16* Bg = Bm + (long)n0*ldb;
    const int NT = K >> 6;

    stageT<128>(Ag, lda, As[0], w, lane);     // 4 loads/thread
    stageT<128>(Bg, ldb, Bs[0], w, lane);     // 4 loads/thread
    int cur = 0;
    for (int t = 0; t < NT; ++t){
        if (t+1 < NT){
            stageT<128>(Ag + (t+1)*64, lda, As[cur^1], w, lane);
            stageT<128>(Bg + (t+1)*64, ldb, Bs[cur^1], w, lane);
            // wait for tile t's 8 loads (oldest); leave tile t+1's 8 in flight (T4)
            asm volatile("s_waitcnt vmcnt(8)" ::: "memory");
        } else {
            asm volatile("s_waitcnt vmcnt(0)" ::: "memory");
        }
        __builtin_amdgcn_sched_barrier(0);
        __builtin_amdgcn_s_barrier();          // tile t fully in LDS for all waves
        #pragma unroll
        for (int kk=0;kk<2;++kk){
            const int sa = ((kk*64 + lg*16) ^ ((lr&7)<<4));
            bf16x8 af[4], bfr[4];
            #pragma unroll
            for (int m=0;m<4;++m)
                af[m] = *(const bf16x8*)((const char*)&As[cur][0] + (wr*64 + m*16 + lr)*128 + sa);
            #pragma unroll
            for (int n=0;n<4;++n)
                bfr[n] = *(const bf16x8*)((const char*)&Bs[cur][0] + (wc*64 + n*16 + lr)*128 + sa);
            #pragma unroll
            for (int m=0;m<4;++m)
                #pragma unroll
                for (int n=0;n<4;++n)
                    acc[m][n] = __builtin_amdgcn_mfma_f32_16x16x32_bf16(af[m], bfr[n], acc[m][n], 0, 0, 0);
        }
        __builtin_amdgcn_s_barrier();          // all waves done reading buf[cur]
        cur ^= 1;
    }

    #pragma unroll
    for (int m=0;m<4;++m){
        #pragma unroll
        for (int n=0;n<4;++n){
            int col = n0 + wc*64 + n*16 + lr;
            if (col >= N) continue;
            #pragma unroll
            for (int e=0;e<4;++e){
                int row = m0 + wr*64 + m*16 + lg*4 + e;
                if (row >= M) continue;
                float v = acc[m][n][e]*scale;
                if (bias) v += bias[col];
                if (act) v = gelu_f(v);
                if (Rp) v += Rp[(long)bz*sR + (long)row*ldc + col];
                if (obf) ((__bf16*)Cp)[(long)bz*sC + (long)row*ldc + col] = (__bf16)v;
                else     ((float*)Cp)[(long)bz*sC + (long)row*ldc + col] = v;
            }
        }
    }
}

// ---------------- MFMA flash attention: block = (q-tile 64, head, batch), 4 waves ----------------
__global__ __launch_bounds__(256) void attn2(const __bf16* __restrict__ QKV, __bf16* __restrict__ O)
{
    __shared__ __align__(16) __bf16 Ks[64*64];
    __shared__ __align__(16) __bf16 VT[64*72];
    __shared__ __align__(16) __bf16 Ps[64*72];
    const int qt=blockIdx.x, h=blockIdx.y, b=blockIdx.z;
    const int tid=threadIdx.x, w=tid>>6, lane=tid&63;
    const int lr=lane&15, lg=lane>>4;
    const __bf16* base = QKV + (long)b*NTOK*1152;
    const long qrow = qt*64 + w*16 + lr;
    const bf16x8 qa0 = *(const bf16x8*)(base + qrow*1152 + h*64 + lg*8);
    const bf16x8 qa1 = *(const bf16x8*)(base + qrow*1152 + h*64 + 32 + lg*8);

    f32x4 oacc[4];
    float mo[4], lo[4];
    #pragma unroll
    for (int e=0;e<4;++e){ mo[e]=-1e30f; lo[e]=0.f; }
    #pragma unroll
    for (int n=0;n<4;++n) oacc[n]=(f32x4){0.f,0.f,0.f,0.f};

    for (int kt=0; kt<8; ++kt){
        __syncthreads();   // previous iteration's LDS readers done
        #pragma unroll
        for (int j=0;j<2;++j){
            int i = w*2+j;
            int ol = i*1024 + lane*16;
            int row = ol>>7, colb = ol&127;
            int sc = colb ^ ((row&7)<<4);
            gload16((const char*)base + ((long)(kt*64+row)*1152 + 384 + h*64)*2 + sc,
                    (char*)Ks + i*1024);
        }
        #pragma unroll
        for (int rep=0;rep<2;++rep){
            int c = tid + rep*256;
            int kv = c & 63, d8 = c >> 6;
            bf16x8 vv = *(const bf16x8*)(base + (long)(kt*64+kv)*1152 + 768 + h*64 + d8*8);
            #pragma unroll
            for (int jj=0;jj<8;++jj) VT[(d8*8+jj)*72 + kv] = vv[jj];
        }
        __syncthreads();   // staging visible

        f32x4 s[4];
        #pragma unroll
        for (int n=0;n<4;++n) s[n]=(f32x4){0.f,0.f,0.f,0.f};
        #pragma unroll
        for (int kk=0;kk<2;++kk){
            const int sa = ((kk*64 + lg*16) ^ ((lr&7)<<4));
            #pragma unroll
            for (int n=0;n<4;++n){
                bf16x8 kb = *(const bf16x8*)((const char*)Ks + (n*16+lr)*128 + sa);
                s[n] = __builtin_amdgcn_mfma_f32_16x16x32_bf16(kk? qa1:qa0, kb, s[n], 0,0,0);
            }
        }
        #pragma unroll
        for (int n=0;n<4;++n){
            int col = kt*64 + n*16 + lr;
            bool bad = col >= NTOK;
            #pragma unroll
            for (int e=0;e<4;++e) s[n][e] = bad ? -1e30f : s[n][e]*0.125f;
        }
        #pragma unroll
        for (int e=0;e<4;++e){
            float rm = fmaxf(fmaxf(s[0][e],s[1][e]), fmaxf(s[2][e],s[3][e]));
            rm = fmaxf(rm, __shfl_xor(rm,1));
            rm = fmaxf(rm, __shfl_xor(rm,2));
            rm = fmaxf(rm, __shfl_xor(rm,4));
            rm = fmaxf(rm, __shfl_xor(rm,8));
            float mn = fmaxf(mo[e], rm);
            float al = __expf(mo[e]-mn);
            float rs = 0.f;
            #pragma unroll
            for (int n=0;n<4;++n){ float p=__expf(s[n][e]-mn); s[n][e]=p; rs+=p; }
            rs += __shfl_xor(rs,1); rs += __shfl_xor(rs,2);
            rs += __shfl_xor(rs,4); rs += __shfl_xor(rs,8);
            lo[e] = lo[e]*al + rs; mo[e]=mn;
            #pragma unroll
            for (int n=0;n<4;++n) oacc[n][e] *= al;
        }
        #pragma unroll
        for (int n=0;n<4;++n)
            #pragma unroll
            for (int e=0;e<4;++e)
                Ps[(w*16+lg*4+e)*72 + n*16+lr] = (__bf16)s[n][e];
        #pragma unroll
        for (int kk=0;kk<2;++kk){
            bf16x8 pa = *(const bf16x8*)&Ps[(w*16+lr)*72 + kk*32 + lg*8];
            #pragma unroll
            for (int n=0;n<4;++n){
                bf16x8 vf = *(const bf16x8*)&VT[(n*16+lr)*72 + kk*32 + lg*8];
                oacc[n] = __builtin_amdgcn_mfma_f32_16x16x32_bf16(pa, vf, oacc[n], 0,0,0);
            }
        }
    }
    #pragma unroll
    for (int e=0;e<4;++e){
        int q = qt*64 + w*16 + lg*4 + e;
        if (q < NTOK){
            float inv = 1.f/lo[e];
            __bf16* op = O + ((long)b*NTOK + q)*TD + h*64;
            #pragma unroll
            for (int n=0;n<4;++n)
                op[n*16+lr] = (__bf16)(oacc[n][e]*inv);
        }
    }
}

// ---------------- LayerNorm row of 384 (fp32 in, bf16 out) ----------------
__global__ __launch_bounds__(128) void ln_kernel(const float* __restrict__ Xp, __bf16* __restrict__ Y,
    const float* __restrict__ W, const float* __restrict__ Bp)
{
    long r = blockIdx.x;
    int t = threadIdx.x;
    const float* x = Xp + r*TD;
    float v0 = x[t], v1 = x[t+128], v2 = x[t+256];
    float s = v0+v1+v2;
    float q = v0*v0+v1*v1+v2*v2;
    #pragma unroll
    for (int w=1; w<64; w<<=1){ s += __shfl_xor(s,w); q += __shfl_xor(q,w); }
    __shared__ float sm[2][2];
    if ((t&63)==0){ sm[t>>6][0]=s; sm[t>>6][1]=q; }
    __syncthreads();
    float S = sm[0][0]+sm[1][0];
    float Q = sm[0][1]+sm[1][1];
    float mean = S*(1.f/384.f);
    float var  = Q*(1.f/384.f) - mean*mean;
    float rstd = rsqrtf(var + 1e-6f);
    __bf16* y = Y + r*TD;
    y[t]     = (__bf16)((v0-mean)*rstd*W[t]     + Bp[t]);
    y[t+128] = (__bf16)((v1-mean)*rstd*W[t+128] + Bp[t+128]);
    y[t+256] = (__bf16)((v2-mean)*rstd*W[t+256] + Bp[t+256]);
}

// ---------------- weight fp32 -> bf16 ----------------
__global__ void wconv_kernel(const float* __restrict__ s, __bf16* __restrict__ d, int n4){
    int i = blockIdx.x*256 + threadIdx.x;
    if (i < n4){
        float4 v = ((const float4*)s)[i];
        bf16x4 p; p[0]=(__bf16)v.x; p[1]=(__bf16)v.y; p[2]=(__bf16)v.z; p[3]=(__bf16)v.w;
        ((bf16x4*)d)[i] = p;
    }
}

// ---------------- im2col (bf16 out) ----------------
__global__ void im2col_kernel(const float* __restrict__ in, __bf16* __restrict__ outp)
{
    long idx = (long)blockIdx.x*256 + threadIdx.x;
    if (idx >= (long)7680*1792) return;
    int k = (int)(idx % 1792);
    long m = idx / 1792;
    int pw = (int)(m % 40);
    long t2 = m / 40;
    int ph = (int)(t2 % 12);
    int b  = (int)(t2 / 12);
    int kw = k & 15, kh = (k >> 4) & 15, c = k >> 8;
    outp[idx] = (__bf16)in[(((long)(b*7 + c)*192) + ph*16 + kh)*640 + pw*16 + kw];
}

// ---------------- assemble x = [cls; conv_out] + pos (fp32) ----------------
__global__ void assemble_kernel(const float* __restrict__ CO, const float* __restrict__ cls,
    const float* __restrict__ pos, float* __restrict__ X)
{
    long idx = (long)blockIdx.x*256 + threadIdx.x;
    if (idx >= (long)NROWS*TD) return;
    int d = (int)(idx % TD);
    long r = idx / TD;
    int tok = (int)(r % NTOK);
    int b   = (int)(r / NTOK);
    float v = (tok == 0) ? cls[d] : CO[((long)b*480 + tok-1)*TD + d];
    X[idx] = v + pos[tok*TD + d];
}

// ---------------- pose maps ----------------
__global__ __launch_bounds__(256) void pose_maps_kernel(const float* __restrict__ PA,
    float* __restrict__ attn_map, float* __restrict__ masked_map)
{
    int i = blockIdx.x;   // 0..39
    int b = blockIdx.y;   // 0..15
    int t = threadIdx.x;
    float accA[12], accM[12];
    #pragma unroll
    for (int j=0;j<12;++j){ accA[j]=0.f; accM[j]=0.f; }
    for (int a = t; a < 480; a += 256) {
        const float* row = PA + ((long)(b*480 + a))*480 + i;
        float v[12];
        float mx = -1e30f;
        #pragma unroll
        for (int j=0;j<12;++j){ v[j] = row[40*j]; mx = fmaxf(mx, v[j]); }
        float sum = 0.f;
        #pragma unroll
        for (int j=0;j<12;++j){ v[j] = expf(v[j]-mx); sum += v[j]; }
        float invs = 1.f/sum;
        #pragma unroll
        for (int j=0;j<12;++j) v[j] *= invs;
        float srt[12];
        #pragma unroll
        for (int j=0;j<12;++j){
            float x = v[j]; int p = j;
            while (p > 0 && srt[p-1] > x){ srt[p]=srt[p-1]; --p; }
            srt[p]=x;
        }
        float med = srt[5];
        #pragma unroll
        for (int j=0;j<12;++j){
            accA[j] += v[j];
            accM[j] += (v[j] > med) ? 0.f : v[j];
        }
    }
    __shared__ float redA[256*12];
    __shared__ float redM[256*12];
    #pragma unroll
    for (int j=0;j<12;++j){ redA[t*12+j]=accA[j]; redM[t*12+j]=accM[j]; }
    __syncthreads();
    for (int sgap=128; sgap>0; sgap>>=1){
        if (t < sgap){
            #pragma unroll
            for (int j=0;j<12;++j){
                redA[t*12+j] += redA[(t+sgap)*12+j];
                redM[t*12+j] += redM[(t+sgap)*12+j];
            }
        }
        __syncthreads();
    }
    if (t < 12){
        attn_map  [(b*12 + t)*40 + i] = redA[t] * (1.f/480.f);
        masked_map[(b*12 + t)*40 + i] = redM[t] * (1.f/480.f) * (1.f/24.f);
    }
}

// ---------------- column-sum of pose V (bf16 in), 4-way row-split ----------------
__global__ __launch_bounds__(384) void colsum4_kernel(const __bf16* __restrict__ QKV2, float* __restrict__ CS4)
{
    int b = blockIdx.x, j = blockIdx.y, c = threadIdx.x;
    const __bf16* p = QKV2 + (long)b*480*1152 + 768 + c;
    float s = 0.f;
    for (int a = j*120; a < j*120+120; ++a) s += (float)p[(long)a*1152];
    CS4[((long)b*4 + j)*384 + c] = s;
}

// ---------------- final pose output: LN(40*colsum @ pose_w^T + pose_b) ----------------
__global__ __launch_bounds__(384) void pose_final_kernel(const float* __restrict__ CS4,
    const float* __restrict__ PW, const float* __restrict__ PB,
    const float* __restrict__ NW, const float* __restrict__ NBb, float* __restrict__ out)
{
    int b = blockIdx.x, c = threadIdx.x;
    const float* s0 = CS4 + (long)b*1536;
    __shared__ float sv[384];
    sv[c] = s0[c] + s0[384+c] + s0[768+c] + s0[1152+c];
    __syncthreads();
    const float* wr = PW + (long)c*384;
    float acc = 0.f;
    for (int k = 0; k < 384; ++k) acc += sv[k]*wr[k];
    acc = 40.f*acc + PB[c];
    float s = acc, q = acc*acc;
    #pragma unroll
    for (int w=1; w<64; w<<=1){ s += __shfl_xor(s,w); q += __shfl_xor(q,w); }
    __shared__ float sm[6][2];
    if ((c & 63) == 0){ sm[c>>6][0]=s; sm[c>>6][1]=q; }
    __syncthreads();
    float S=0.f, Q=0.f;
    for (int i=0;i<6;++i){ S+=sm[i][0]; Q+=sm[i][1]; }
    float mean = S*(1.f/384.f);
    float var  = Q*(1.f/384.f) - mean*mean;
    float rstd = rsqrtf(var + 1e-6f);
    out[b*384 + c] = (acc-mean)*rstd*NW[c] + NBb[c];
}

extern "C" void kernel_launch(void* const* d_in, const int* in_sizes, int n_in,
                              void* d_out, int out_size, void* d_ws, size_t ws_size,
                              hipStream_t stream)
{
    const float* input  = (const float*)d_in[0];
    const float* conv_w = (const float*)d_in[1];
    const float* conv_b = (const float*)d_in[2];
    const float* cls    = (const float*)d_in[3];
    const float* pos    = (const float*)d_in[4];
    const float* ln1w   = (const float*)d_in[5];
    const float* ln1b   = (const float*)d_in[6];
    const float* qkvw   = (const float*)d_in[7];
    const float* qkvb   = (const float*)d_in[8];
    const float* projw  = (const float*)d_in[9];
    const float* projb  = (const float*)d_in[10];
    const float* ln2w   = (const float*)d_in[11];
    const float* ln2b   = (const float*)d_in[12];
    const float* fc1w   = (const float*)d_in[13];
    const float* fc1b   = (const float*)d_in[14];
    const float* fc2w   = (const float*)d_in[15];
    const float* fc2b   = (const float*)d_in[16];
    const float* normw  = (const float*)d_in[17];
    const float* normb  = (const float*)d_in[18];
    const float* toqkvw = (const float*)d_in[19];
    const float* posew  = (const float*)d_in[20];
    const float* poseb  = (const float*)d_in[21];
    float* out = (float*)d_out;
    float* ws  = (float*)d_ws;

    // ---- workspace layout (float offsets); activation row-dim padded to MPAD=7808 ----
    __bf16* WB   = (__bf16*)ws;                    // 22,364,160 bf16 = 11,182,080 f
    float*  X    = ws + 11182080;                  // 7696*384 fp32
    __bf16* Hbf  = (__bf16*)(ws + 14137344);       // 7808*384 bf16  = 1,499,136 f
    __bf16* QKVb = (__bf16*)(ws + 15636480);       // 7808*1536 bf16 = 5,996,544 f
    __bf16* Obuf = (__bf16*)(ws + 21633024);       // 7808*384 bf16  = 1,499,136 f
    float*  PAb  = ws + 23132160;                  // 16*480*480 fp32 (also conv tmp)
    float*  CS4  = PAb + 3686400;                  // 16*4*384 fp32
    __bf16* IM2C = QKVb;                           // alias spans QKVb+Obuf (pre-layer only)

    __bf16* Wconv = WB;
    __bf16* Wqkv  = WB + 688128;
    __bf16* Wproj = WB + 5996544;
    __bf16* Wfc1  = WB + 7766016;
    __bf16* Wfc2  = WB + 14843904;
    __bf16* Wtoq  = WB + 21921792;

    // ---- weights -> bf16 ----
    wconv_kernel<<<dim3((172032+255)/256), 256, 0, stream>>>(conv_w, Wconv, 172032);
    wconv_kernel<<<dim3((1327104+255)/256), 256, 0, stream>>>(qkvw,  Wqkv, 1327104);
    wconv_kernel<<<dim3((442368+255)/256), 256, 0, stream>>>(projw, Wproj, 442368);
    wconv_kernel<<<dim3((1769472+255)/256), 256, 0, stream>>>(fc1w,  Wfc1, 1769472);
    wconv_kernel<<<dim3((1769472+255)/256), 256, 0, stream>>>(fc2w,  Wfc2, 1769472);
    wconv_kernel<<<dim3((110592+255)/256), 256, 0, stream>>>(toqkvw, Wtoq, 110592);

    // ---- patch embed ----
    {
        long total = (long)7680*1792;
        im2col_kernel<<<dim3((unsigned)((total+255)/256)), 256, 0, stream>>>(input, IM2C);
    }
    mgemm<<<dim3(3, 60, 1), 256, 0, stream>>>(IM2C, 1792, 0, Wconv, 1792, 0,
        PAb, 384, 0, conv_b, nullptr, 0, 7680, 384, 1792, 1.f, 0, 0);
    assemble_kernel<<<dim3((NROWS*TD+255)/256), 256, 0, stream>>>(PAb, cls, pos, X);

    // ---- transformer layers ----
    for (int i = 0; i < 12; ++i) {
        ln_kernel<<<dim3(NROWS), 128, 0, stream>>>(X, Hbf, ln1w + i*384, ln1b + i*384);
        mgemm<<<dim3(9, 61, 1), 256, 0, stream>>>(Hbf, 384, 0, Wqkv + (long)i*1152*384, 384, 0,
            QKVb, 1152, 0, qkvb + i*1152, nullptr, 0, NROWS, 1152, 384, 1.f, 0, 1);
        attn2<<<dim3(8, NHEAD, NB), 256, 0, stream>>>(QKVb, Obuf);
        mgemm<<<dim3(3, 61, 1), 256, 0, stream>>>(Obuf, 384, 0, Wproj + (long)i*384*384, 384, 0,
            X, 384, 0, projb + i*384, X, 0, NROWS, 384, 384, 1.f, 0, 0);
        ln_kernel<<<dim3(NROWS), 128, 0, stream>>>(X, Hbf, ln2w + i*384, ln2b + i*384);
        mgemm<<<dim3(12, 61, 1), 256, 0, stream>>>(Hbf, 384, 0, Wfc1 + (long)i*1536*384, 384, 0,
            QKVb, 1536, 0, fc1b + i*1536, nullptr, 0, NROWS, 1536, 384, 1.f, 1, 1);
        mgemm<<<dim3(3, 61, 1), 256, 0, stream>>>(QKVb, 1536, 0, Wfc2 + (long)i*384*1536, 1536, 0,
            X, 384, 0, fc2b + i*384, X, 0, NROWS, 384, 1536, 1.f, 0, 0);
    }
    ln_kernel<<<dim3(NROWS), 128, 0, stream>>>(X, Hbf, normw, normb);

    // ---- pose head ----
    mgemm<<<dim3(9, 4, 16), 256, 0, stream>>>(Hbf + 384, 384, (long)481*384,
        Wtoq, 384, 0, QKVb, 1152, (long)480*1152, nullptr, nullptr, 0, 480, 1152, 384, 1.f, 0, 1);
    mgemm<<<dim3(4, 4, 16), 256, 0, stream>>>(QKVb, 1152, (long)480*1152,
        QKVb + 384, 1152, (long)480*1152, PAb, 480, (long)480*480, nullptr, nullptr, 0,
        480, 480, 384, 0.05103f*0.01f, 0, 0);
    pose_maps_kernel<<<dim3(40, 16), 256, 0, stream>>>(PAb, out + 6144, out + 13824);
    colsum4_kernel<<<dim3(16, 4), 384, 0, stream>>>(QKVb, CS4);
    pose_final_kernel<<<dim3(16), 384, 0, stream>>>(CS4, posew, poseb, normw, normb, out);
}

// Round 6
// 2414.997 us; speedup vs baseline: 1.1671x; 1.1671x over previous
//
#include <hip/hip_runtime.h>
#include <hip/hip_bf16.h>

#define TD 384
#define NHEAD 6
#define NFF 1536
#define NB 16
#define NTOK 481
#define NROWS (NB*NTOK)   // 7696

typedef __attribute__((ext_vector_type(8))) __bf16 bf16x8;
typedef __attribute__((ext_vector_type(4))) __bf16 bf16x4;
typedef __attribute__((ext_vector_type(4))) float f32x4;

static __device__ __forceinline__ float gelu_f(float v){
    return 0.5f*v*(1.0f + erff(v*0.70710678118654752f));
}

static __device__ __forceinline__ void gload16(const void* g, void* l){
    __builtin_amdgcn_global_load_lds((const __attribute__((address_space(1))) void*)g,
                                     (__attribute__((address_space(3))) void*)l, 16, 0, 0);
}

// stage ROWS x 64 bf16 tile (row-major, 128B rows) into linear LDS via global_load_lds,
// with XOR-swizzled SOURCE address so that a swizzled ds_read returns linear data (T2, rule 21).
template<int ROWS>
static __device__ __forceinline__ void stageT(const __bf16* g, int ldel, __bf16* lds, int w, int lane){
    #pragma unroll
    for (int j = 0; j < ROWS/32; ++j){
        int i = w*(ROWS/32) + j;
        int ol = i*1024 + lane*16;
        int row = ol >> 7, colb = ol & 127;
        int sc = colb ^ ((row & 7) << 4);
        gload16((const char*)g + (long)row*ldel*2 + sc, (char*)lds + i*1024);
    }
}

// ---------------- bf16 MFMA GEMM: C = scale*(A @ B^T) + bias [+gelu] [+R fp32] ----------------
// A: (M,K) bf16 row-major lda (rows padded in-allocation); B: (N,K) bf16 ldb; C fp32/bf16.
// K % 64 == 0, K/64 >= 2. 256 thr = 4 waves (2x2); tile 64x128, wave owns 32x64.
// Triple-buffered LDS, 2-tiles-ahead prefetch, counted vmcnt(6), ONE barrier per K-step.
__global__ __launch_bounds__(256) void mgemm(
    const __bf16* __restrict__ A, int lda, long sA,
    const __bf16* __restrict__ Bm, int ldb, long sB,
    void* __restrict__ Cp, int ldc, long sC,
    const float* __restrict__ bias,
    const float* __restrict__ Rp, long sR,
    int M, int N, int K, float scale, int act, int obf)
{
    __shared__ __align__(16) __bf16 As[3][64*64];
    __shared__ __align__(16) __bf16 Bs[3][128*64];
    const int bz = blockIdx.z;
    A  += (long)bz*sA; Bm += (long)bz*sB;

    // bijective XCD-chunked swizzle (T1, m204)
    const int nwg = gridDim.x*gridDim.y;
    const int id  = blockIdx.y*gridDim.x + blockIdx.x;
    const int q8  = nwg >> 3, r8 = nwg & 7;
    const int xcd = id & 7, sub = id >> 3;
    const int nid = (xcd < r8 ? xcd*(q8+1) : r8*(q8+1) + (xcd-r8)*q8) + sub;
    const int m0 = (nid / gridDim.x) * 64, n0 = (nid % gridDim.x) * 128;

    const int tid = threadIdx.x;
    const int w = tid >> 6, lane = tid & 63;
    const int wr = w >> 1, wc = w & 1;
    const int lr = lane & 15, lg = lane >> 4;

    f32x4 acc[2][4];
    #pragma unroll
    for (int m=0;m<2;++m)
        #pragma unroll
        for (int n=0;n<4;++n)
            acc[m][n] = (f32x4){0.f,0.f,0.f,0.f};

    const __bf16* Ag = A + (long)m0*lda;
    const __bf16* Bg = Bm + (long)n0*ldb;
    const int NT = K >> 6;

    // prologue: tiles 0 and 1 in flight (12 loads/thread total: 6 per tile)
    stageT<64>(Ag,        lda, As[0], w, lane);
    stageT<128>(Bg,       ldb, Bs[0], w, lane);
    stageT<64>(Ag + 64,   lda, As[1], w, lane);
    stageT<128>(Bg + 64,  ldb, Bs[1], w, lane);

    for (int t = 0; t < NT; ++t){
        // ensure tile t resident; keep tile t+1's 6 loads in flight (T4 counted vmcnt)
        if (t+1 < NT) asm volatile("s_waitcnt vmcnt(6)" ::: "memory");
        else          asm volatile("s_waitcnt vmcnt(0)" ::: "memory");
        __builtin_amdgcn_sched_barrier(0);
        __builtin_amdgcn_s_barrier();
        // after this barrier every wave has finished reading buf[(t+2)%3] (its
        // iter t-1 reads completed via that iter's lgkmcnt(0)) -> safe to overwrite
        if (t+2 < NT){
            stageT<64>(Ag + (t+2)*64,  lda, As[(t+2)%3], w, lane);
            stageT<128>(Bg + (t+2)*64, ldb, Bs[(t+2)%3], w, lane);
        }
        const __bf16* Ac = As[t%3];
        const __bf16* Bc = Bs[t%3];
        bf16x8 af[2][2], bfr[2][4];
        #pragma unroll
        for (int kk=0;kk<2;++kk){
            const int sa = ((kk*64 + lg*16) ^ ((lr&7)<<4));
            #pragma unroll
            for (int m=0;m<2;++m)
                af[kk][m] = *(const bf16x8*)((const char*)Ac + (wr*32 + m*16 + lr)*128 + sa);
            #pragma unroll
            for (int n=0;n<4;++n)
                bfr[kk][n] = *(const bf16x8*)((const char*)Bc + (wc*64 + n*16 + lr)*128 + sa);
        }
        asm volatile("s_waitcnt lgkmcnt(0)" ::: "memory");
        __builtin_amdgcn_sched_barrier(0);
        __builtin_amdgcn_s_setprio(1);
        #pragma unroll
        for (int kk=0;kk<2;++kk)
            #pragma unroll
            for (int m=0;m<2;++m)
                #pragma unroll
                for (int n=0;n<4;++n)
                    acc[m][n] = __builtin_amdgcn_mfma_f32_16x16x32_bf16(af[kk][m], bfr[kk][n], acc[m][n], 0, 0, 0);
        __builtin_amdgcn_s_setprio(0);
    }

    #pragma unroll
    for (int m=0;m<2;++m){
        #pragma unroll
        for (int n=0;n<4;++n){
            int col = n0 + wc*64 + n*16 + lr;
            if (col >= N) continue;
            #pragma unroll
            for (int e=0;e<4;++e){
                int row = m0 + wr*32 + m*16 + lg*4 + e;
                if (row >= M) continue;
                float v = acc[m][n][e]*scale;
                if (bias) v += bias[col];
                if (act) v = gelu_f(v);
                if (Rp) v += Rp[(long)bz*sR + (long)row*ldc + col];
                if (obf) ((__bf16*)Cp)[(long)bz*sC + (long)row*ldc + col] = (__bf16)v;
                else     ((float*)Cp)[(long)bz*sC + (long)row*ldc + col] = v;
            }
        }
    }
}

// ---------------- MFMA flash attention: block = (q-tile 64, head, batch), 4 waves ----------------
__global__ __launch_bounds__(256) void attn2(const __bf16* __restrict__ QKV, __bf16* __restrict__ O)
{
    __shared__ __align__(16) __bf16 Ks[64*64];
    __shared__ __align__(16) __bf16 VT[64*72];
    __shared__ __align__(16) __bf16 Ps[64*72];
    const int qt=blockIdx.x, h=blockIdx.y, b=blockIdx.z;
    const int tid=threadIdx.x, w=tid>>6, lane=tid&63;
    const int lr=lane&15, lg=lane>>4;
    const __bf16* base = QKV + (long)b*NTOK*1152;
    const long qrow = qt*64 + w*16 + lr;
    const bf16x8 qa0 = *(const bf16x8*)(base + qrow*1152 + h*64 + lg*8);
    const bf16x8 qa1 = *(const bf16x8*)(base + qrow*1152 + h*64 + 32 + lg*8);

    f32x4 oacc[4];
    float mo[4], lo[4];
    #pragma unroll
    for (int e=0;e<4;++e){ mo[e]=-1e30f; lo[e]=0.f; }
    #pragma unroll
    for (int n=0;n<4;++n) oacc[n]=(f32x4){0.f,0.f,0.f,0.f};

    for (int kt=0; kt<8; ++kt){
        __syncthreads();   // previous iteration's LDS readers done
        #pragma unroll
        for (int j=0;j<2;++j){
            int i = w*2+j;
            int ol = i*1024 + lane*16;
            int row = ol>>7, colb = ol&127;
            int sc = colb ^ ((row&7)<<4);
            gload16((const char*)base + ((long)(kt*64+row)*1152 + 384 + h*64)*2 + sc,
                    (char*)Ks + i*1024);
        }
        #pragma unroll
        for (int rep=0;rep<2;++rep){
            int c = tid + rep*256;
            int kv = c & 63, d8 = c >> 6;
            bf16x8 vv = *(const bf16x8*)(base + (long)(kt*64+kv)*1152 + 768 + h*64 + d8*8);
            #pragma unroll
            for (int jj=0;jj<8;++jj) VT[(d8*8+jj)*72 + kv] = vv[jj];
        }
        __syncthreads();   // staging visible

        f32x4 s[4];
        #pragma unroll
        for (int n=0;n<4;++n) s[n]=(f32x4){0.f,0.f,0.f,0.f};
        #pragma unroll
        for (int kk=0;kk<2;++kk){
            const int sa = ((kk*64 + lg*16) ^ ((lr&7)<<4));
            #pragma unroll
            for (int n=0;n<4;++n){
                bf16x8 kb = *(const bf16x8*)((const char*)Ks + (n*16+lr)*128 + sa);
                s[n] = __builtin_amdgcn_mfma_f32_16x16x32_bf16(kk? qa1:qa0, kb, s[n], 0,0,0);
            }
        }
        #pragma unroll
        for (int n=0;n<4;++n){
            int col = kt*64 + n*16 + lr;
            bool bad = col >= NTOK;
            #pragma unroll
            for (int e=0;e<4;++e) s[n][e] = bad ? -1e30f : s[n][e]*0.125f;
        }
        #pragma unroll
        for (int e=0;e<4;++e){
            float rm = fmaxf(fmaxf(s[0][e],s[1][e]), fmaxf(s[2][e],s[3][e]));
            rm = fmaxf(rm, __shfl_xor(rm,1));
            rm = fmaxf(rm, __shfl_xor(rm,2));
            rm = fmaxf(rm, __shfl_xor(rm,4));
            rm = fmaxf(rm, __shfl_xor(rm,8));
            float mn = fmaxf(mo[e], rm);
            float al = __expf(mo[e]-mn);
            float rs = 0.f;
            #pragma unroll
            for (int n=0;n<4;++n){ float p=__expf(s[n][e]-mn); s[n][e]=p; rs+=p; }
            rs += __shfl_xor(rs,1); rs += __shfl_xor(rs,2);
            rs += __shfl_xor(rs,4); rs += __shfl_xor(rs,8);
            lo[e] = lo[e]*al + rs; mo[e]=mn;
            #pragma unroll
            for (int n=0;n<4;++n) oacc[n][e] *= al;
        }
        #pragma unroll
        for (int n=0;n<4;++n)
            #pragma unroll
            for (int e=0;e<4;++e)
                Ps[(w*16+lg*4+e)*72 + n*16+lr] = (__bf16)s[n][e];
        #pragma unroll
        for (int kk=0;kk<2;++kk){
            bf16x8 pa = *(const bf16x8*)&Ps[(w*16+lr)*72 + kk*32 + lg*8];
            #pragma unroll
            for (int n=0;n<4;++n){
                bf16x8 vf = *(const bf16x8*)&VT[(n*16+lr)*72 + kk*32 + lg*8];
                oacc[n] = __builtin_amdgcn_mfma_f32_16x16x32_bf16(pa, vf, oacc[n], 0,0,0);
            }
        }
    }
    #pragma unroll
    for (int e=0;e<4;++e){
        int q = qt*64 + w*16 + lg*4 + e;
        if (q < NTOK){
            float inv = 1.f/lo[e];
            __bf16* op = O + ((long)b*NTOK + q)*TD + h*64;
            #pragma unroll
            for (int n=0;n<4;++n)
                op[n*16+lr] = (__bf16)(oacc[n][e]*inv);
        }
    }
}

// ---------------- LayerNorm row of 384 (fp32 in, bf16 out) ----------------
__global__ __launch_bounds__(128) void ln_kernel(const float* __restrict__ Xp, __bf16* __restrict__ Y,
    const float* __restrict__ W, const float* __restrict__ Bp)
{
    long r = blockIdx.x;
    int t = threadIdx.x;
    const float* x = Xp + r*TD;
    float v0 = x[t], v1 = x[t+128], v2 = x[t+256];
    float s = v0+v1+v2;
    float q = v0*v0+v1*v1+v2*v2;
    #pragma unroll
    for (int w=1; w<64; w<<=1){ s += __shfl_xor(s,w); q += __shfl_xor(q,w); }
    __shared__ float sm[2][2];
    if ((t&63)==0){ sm[t>>6][0]=s; sm[t>>6][1]=q; }
    __syncthreads();
    float S = sm[0][0]+sm[1][0];
    float Q = sm[0][1]+sm[1][1];
    float mean = S*(1.f/384.f);
    float var  = Q*(1.f/384.f) - mean*mean;
    float rstd = rsqrtf(var + 1e-6f);
    __bf16* y = Y + r*TD;
    y[t]     = (__bf16)((v0-mean)*rstd*W[t]     + Bp[t]);
    y[t+128] = (__bf16)((v1-mean)*rstd*W[t+128] + Bp[t+128]);
    y[t+256] = (__bf16)((v2-mean)*rstd*W[t+256] + Bp[t+256]);
}

// ---------------- weight fp32 -> bf16 ----------------
__global__ void wconv_kernel(const float* __restrict__ s, __bf16* __restrict__ d, int n4){
    int i = blockIdx.x*256 + threadIdx.x;
    if (i < n4){
        float4 v = ((const float4*)s)[i];
        bf16x4 p; p[0]=(__bf16)v.x; p[1]=(__bf16)v.y; p[2]=(__bf16)v.z; p[3]=(__bf16)v.w;
        ((bf16x4*)d)[i] = p;
    }
}

// ---------------- im2col (bf16 out) ----------------
__global__ void im2col_kernel(const float* __restrict__ in, __bf16* __restrict__ outp)
{
    long idx = (long)blockIdx.x*256 + threadIdx.x;
    if (idx >= (long)7680*1792) return;
    int k = (int)(idx % 1792);
    long m = idx / 1792;
    int pw = (int)(m % 40);
    long t2 = m / 40;
    int ph = (int)(t2 % 12);
    int b  = (int)(t2 / 12);
    int kw = k & 15, kh = (k >> 4) & 15, c = k >> 8;
    outp[idx] = (__bf16)in[(((long)(b*7 + c)*192) + ph*16 + kh)*640 + pw*16 + kw];
}

// ---------------- assemble x = [cls; conv_out] + pos (fp32) ----------------
__global__ void assemble_kernel(const float* __restrict__ CO, const float* __restrict__ cls,
    const float* __restrict__ pos, float* __restrict__ X)
{
    long idx = (long)blockIdx.x*256 + threadIdx.x;
    if (idx >= (long)NROWS*TD) return;
    int d = (int)(idx % TD);
    long r = idx / TD;
    int tok = (int)(r % NTOK);
    int b   = (int)(r / NTOK);
    float v = (tok == 0) ? cls[d] : CO[((long)b*480 + tok-1)*TD + d];
    X[idx] = v + pos[tok*TD + d];
}

// ---------------- pose maps ----------------
__global__ __launch_bounds__(256) void pose_maps_kernel(const float* __restrict__ PA,
    float* __restrict__ attn_map, float* __restrict__ masked_map)
{
    int i = blockIdx.x;   // 0..39
    int b = blockIdx.y;   // 0..15
    int t = threadIdx.x;
    float accA[12], accM[12];
    #pragma unroll
    for (int j=0;j<12;++j){ accA[j]=0.f; accM[j]=0.f; }
    for (int a = t; a < 480; a += 256) {
        const float* row = PA + ((long)(b*480 + a))*480 + i;
        float v[12];
        float mx = -1e30f;
        #pragma unroll
        for (int j=0;j<12;++j){ v[j] = row[40*j]; mx = fmaxf(mx, v[j]); }
        float sum = 0.f;
        #pragma unroll
        for (int j=0;j<12;++j){ v[j] = expf(v[j]-mx); sum += v[j]; }
        float invs = 1.f/sum;
        #pragma unroll
        for (int j=0;j<12;++j) v[j] *= invs;
        float srt[12];
        #pragma unroll
        for (int j=0;j<12;++j){
            float x = v[j]; int p = j;
            while (p > 0 && srt[p-1] > x){ srt[p]=srt[p-1]; --p; }
            srt[p]=x;
        }
        float med = srt[5];
        #pragma unroll
        for (int j=0;j<12;++j){
            accA[j] += v[j];
            accM[j] += (v[j] > med) ? 0.f : v[j];
        }
    }
    __shared__ float redA[256*12];
    __shared__ float redM[256*12];
    #pragma unroll
    for (int j=0;j<12;++j){ redA[t*12+j]=accA[j]; redM[t*12+j]=accM[j]; }
    __syncthreads();
    for (int sgap=128; sgap>0; sgap>>=1){
        if (t < sgap){
            #pragma unroll
            for (int j=0;j<12;++j){
                redA[t*12+j] += redA[(t+sgap)*12+j];
                redM[t*12+j] += redM[(t+sgap)*12+j];
            }
        }
        __syncthreads();
    }
    if (t < 12){
        attn_map  [(b*12 + t)*40 + i] = redA[t] * (1.f/480.f);
        masked_map[(b*12 + t)*40 + i] = redM[t] * (1.f/480.f) * (1.f/24.f);
    }
}

// ---------------- column-sum of pose V (bf16 in), 4-way row-split ----------------
__global__ __launch_bounds__(384) void colsum4_kernel(const __bf16* __restrict__ QKV2, float* __restrict__ CS4)
{
    int b = blockIdx.x, j = blockIdx.y, c = threadIdx.x;
    const __bf16* p = QKV2 + (long)b*480*1152 + 768 + c;
    float s = 0.f;
    for (int a = j*120; a < j*120+120; ++a) s += (float)p[(long)a*1152];
    CS4[((long)b*4 + j)*384 + c] = s;
}

// ---------------- final pose output: LN(40*colsum @ pose_w^T + pose_b) ----------------
__global__ __launch_bounds__(384) void pose_final_kernel(const float* __restrict__ CS4,
    const float* __restrict__ PW, const float* __restrict__ PB,
    const float* __restrict__ NW, const float* __restrict__ NBb, float* __restrict__ out)
{
    int b = blockIdx.x, c = threadIdx.x;
    const float* s0 = CS4 + (long)b*1536;
    __shared__ float sv[384];
    sv[c] = s0[c] + s0[384+c] + s0[768+c] + s0[1152+c];
    __syncthreads();
    const float* wr = PW + (long)c*384;
    float acc = 0.f;
    for (int k = 0; k < 384; ++k) acc += sv[k]*wr[k];
    acc = 40.f*acc + PB[c];
    float s = acc, q = acc*acc;
    #pragma unroll
    for (int w=1; w<64; w<<=1){ s += __shfl_xor(s,w); q += __shfl_xor(q,w); }
    __shared__ float sm[6][2];
    if ((c & 63) == 0){ sm[c>>6][0]=s; sm[c>>6][1]=q; }
    __syncthreads();
    float S=0.f, Q=0.f;
    for (int i=0;i<6;++i){ S+=sm[i][0]; Q+=sm[i][1]; }
    float mean = S*(1.f/384.f);
    float var  = Q*(1.f/384.f) - mean*mean;
    float rstd = rsqrtf(var + 1e-6f);
    out[b*384 + c] = (acc-mean)*rstd*NW[c] + NBb[c];
}

extern "C" void kernel_launch(void* const* d_in, const int* in_sizes, int n_in,
                              void* d_out, int out_size, void* d_ws, size_t ws_size,
                              hipStream_t stream)
{
    const float* input  = (const float*)d_in[0];
    const float* conv_w = (const float*)d_in[1];
    const float* conv_b = (const float*)d_in[2];
    const float* cls    = (const float*)d_in[3];
    const float* pos    = (const float*)d_in[4];
    const float* ln1w   = (const float*)d_in[5];
    const float* ln1b   = (const float*)d_in[6];
    const float* qkvw   = (const float*)d_in[7];
    const float* qkvb   = (const float*)d_in[8];
    const float* projw  = (const float*)d_in[9];
    const float* projb  = (const float*)d_in[10];
    const float* ln2w   = (const float*)d_in[11];
    const float* ln2b   = (const float*)d_in[12];
    const float* fc1w   = (const float*)d_in[13];
    const float* fc1b   = (const float*)d_in[14];
    const float* fc2w   = (const float*)d_in[15];
    const float* fc2b   = (const float*)d_in[16];
    const float* normw  = (const float*)d_in[17];
    const float* normb  = (const float*)d_in[18];
    const float* toqkvw = (const float*)d_in[19];
    const float* posew  = (const float*)d_in[20];
    const float* poseb  = (const float*)d_in[21];
    float* out = (float*)d_out;
    float* ws  = (float*)d_ws;

    // ---- workspace layout (float offsets); activation row-dim padded to 7808 ----
    __bf16* WB   = (__bf16*)ws;                    // weights bf16
    float*  X    = ws + 11182080;                  // 7696*384 fp32
    __bf16* Hbf  = (__bf16*)(ws + 14137344);       // 7808*384 bf16
    __bf16* QKVb = (__bf16*)(ws + 15636480);       // 7808*1536 bf16
    __bf16* Obuf = (__bf16*)(ws + 21633024);       // 7808*384 bf16
    float*  PAb  = ws + 23132160;                  // 16*480*480 fp32 (also conv tmp)
    float*  CS4  = PAb + 3686400;                  // 16*4*384 fp32
    __bf16* IM2C = QKVb;                           // alias spans QKVb+Obuf (pre-layer only)

    __bf16* Wconv = WB;
    __bf16* Wqkv  = WB + 688128;
    __bf16* Wproj = WB + 5996544;
    __bf16* Wfc1  = WB + 7766016;
    __bf16* Wfc2  = WB + 14843904;
    __bf16* Wtoq  = WB + 21921792;

    // ---- weights -> bf16 ----
    wconv_kernel<<<dim3((172032+255)/256), 256, 0, stream>>>(conv_w, Wconv, 172032);
    wconv_kernel<<<dim3((1327104+255)/256), 256, 0, stream>>>(qkvw,  Wqkv, 1327104);
    wconv_kernel<<<dim3((442368+255)/256), 256, 0, stream>>>(projw, Wproj, 442368);
    wconv_kernel<<<dim3((1769472+255)/256), 256, 0, stream>>>(fc1w,  Wfc1, 1769472);
    wconv_kernel<<<dim3((1769472+255)/256), 256, 0, stream>>>(fc2w,  Wfc2, 1769472);
    wconv_kernel<<<dim3((110592+255)/256), 256, 0, stream>>>(toqkvw, Wtoq, 110592);

    // ---- patch embed ----
    {
        long total = (long)7680*1792;
        im2col_kernel<<<dim3((unsigned)((total+255)/256)), 256, 0, stream>>>(input, IM2C);
    }
    mgemm<<<dim3(3, 120, 1), 256, 0, stream>>>(IM2C, 1792, 0, Wconv, 1792, 0,
        PAb, 384, 0, conv_b, nullptr, 0, 7680, 384, 1792, 1.f, 0, 0);
    assemble_kernel<<<dim3((NROWS*TD+255)/256), 256, 0, stream>>>(PAb, cls, pos, X);

    // ---- transformer layers ----
    for (int i = 0; i < 12; ++i) {
        ln_kernel<<<dim3(NROWS), 128, 0, stream>>>(X, Hbf, ln1w + i*384, ln1b + i*384);
        mgemm<<<dim3(9, 121, 1), 256, 0, stream>>>(Hbf, 384, 0, Wqkv + (long)i*1152*384, 384, 0,
            QKVb, 1152, 0, qkvb + i*1152, nullptr, 0, NROWS, 1152, 384, 1.f, 0, 1);
        attn2<<<dim3(8, NHEAD, NB), 256, 0, stream>>>(QKVb, Obuf);
        mgemm<<<dim3(3, 121, 1), 256, 0, stream>>>(Obuf, 384, 0, Wproj + (long)i*384*384, 384, 0,
            X, 384, 0, projb + i*384, X, 0, NROWS, 384, 384, 1.f, 0, 0);
        ln_kernel<<<dim3(NROWS), 128, 0, stream>>>(X, Hbf, ln2w + i*384, ln2b + i*384);
        mgemm<<<dim3(12, 121, 1), 256, 0, stream>>>(Hbf, 384, 0, Wfc1 + (long)i*1536*384, 384, 0,
            QKVb, 1536, 0, fc1b + i*1536, nullptr, 0, NROWS, 1536, 384, 1.f, 1, 1);
        mgemm<<<dim3(3, 121, 1), 256, 0, stream>>>(QKVb, 1536, 0, Wfc2 + (long)i*384*1536, 1536, 0,
            X, 384, 0, fc2b + i*384, X, 0, NROWS, 384, 1536, 1.f, 0, 0);
    }
    ln_kernel<<<dim3(NROWS), 128, 0, stream>>>(X, Hbf, normw, normb);

    // ---- pose head ----
    mgemm<<<dim3(9, 8, 16), 256, 0, stream>>>(Hbf + 384, 384, (long)481*384,
        Wtoq, 384, 0, QKVb, 1152, (long)480*1152, nullptr, nullptr, 0, 480, 1152, 384, 1.f, 0, 1);
    mgemm<<<dim3(4, 8, 16), 256, 0, stream>>>(QKVb, 1152, (long)480*1152,
        QKVb + 384, 1152, (long)480*1152, PAb, 480, (long)480*480, nullptr, nullptr, 0,
        480, 480, 384, 0.05103f*0.01f, 0, 0);
    pose_maps_kernel<<<dim3(40, 16), 256, 0, stream>>>(PAb, out + 6144, out + 13824);
    colsum4_kernel<<<dim3(16, 4), 384, 0, stream>>>(QKVb, CS4);
    pose_final_kernel<<<dim3(16), 384, 0, stream>>>(CS4, posew, poseb, normw, normb, out);
}

// Round 7
// 1804.543 us; speedup vs baseline: 1.5619x; 1.3383x over previous
//
#include <hip/hip_runtime.h>
#include <hip/hip_bf16.h>

#define TD 384
#define NHEAD 6
#define NFF 1536
#define NB 16
#define NTOK 481
#define NROWS (NB*NTOK)   // 7696

typedef __attribute__((ext_vector_type(8))) __bf16 bf16x8;
typedef __attribute__((ext_vector_type(4))) __bf16 bf16x4;
typedef __attribute__((ext_vector_type(4))) float f32x4;

static __device__ __forceinline__ float gelu_f(float v){
    return 0.5f*v*(1.0f + erff(v*0.70710678118654752f));
}

static __device__ __forceinline__ void gload16(const void* g, void* l){
    __builtin_amdgcn_global_load_lds((const __attribute__((address_space(1))) void*)g,
                                     (__attribute__((address_space(3))) void*)l, 16, 0, 0);
}

// stage ROWS x 64 bf16 tile (row-major, 128B rows) into linear LDS via global_load_lds,
// with XOR-swizzled SOURCE address so that a swizzled ds_read returns linear data (T2, rule 21).
template<int ROWS>
static __device__ __forceinline__ void stageT(const __bf16* g, int ldel, __bf16* lds, int w, int lane){
    #pragma unroll
    for (int j = 0; j < ROWS/32; ++j){
        int i = w*(ROWS/32) + j;
        int ol = i*1024 + lane*16;
        int row = ol >> 7, colb = ol & 127;
        int sc = colb ^ ((row & 7) << 4);
        gload16((const char*)g + (long)row*ldel*2 + sc, (char*)lds + i*1024);
    }
}

// ---------------- bf16 MFMA GEMM: C = scale*(A @ B^T) + bias [+gelu] [+R fp32] ----------------
// A: (M,K) bf16 row-major lda (rows padded in-allocation); B: (N,K) bf16 ldb; C fp32/bf16 (obf).
// K % 64 == 0. 256 thr = 4 waves (2x2); tile 64x64, wave owns 32x32.
// Double-buffered LDS via global_load_lds, counted vmcnt(4), XCD-chunked block swizzle.
// LDS 32KB -> 5 blocks/CU (20 waves) for latency hiding.
__global__ __launch_bounds__(256) void mgemm(
    const __bf16* __restrict__ A, int lda, long sA,
    const __bf16* __restrict__ Bm, int ldb, long sB,
    void* __restrict__ Cp, int ldc, long sC,
    const float* __restrict__ bias,
    const float* __restrict__ Rp, long sR,
    int M, int N, int K, float scale, int act, int obf)
{
    __shared__ __align__(16) __bf16 As[2][64*64];
    __shared__ __align__(16) __bf16 Bs[2][64*64];
    const int bz = blockIdx.z;
    A  += (long)bz*sA; Bm += (long)bz*sB;

    // bijective XCD-chunked swizzle (T1, m204)
    const int nwg = gridDim.x*gridDim.y;
    const int id  = blockIdx.y*gridDim.x + blockIdx.x;
    const int q8  = nwg >> 3, r8 = nwg & 7;
    const int xcd = id & 7, sub = id >> 3;
    const int nid = (xcd < r8 ? xcd*(q8+1) : r8*(q8+1) + (xcd-r8)*q8) + sub;
    const int m0 = (nid / gridDim.x) * 64, n0 = (nid % gridDim.x) * 64;

    const int tid = threadIdx.x;
    const int w = tid >> 6, lane = tid & 63;
    const int wr = w >> 1, wc = w & 1;
    const int lr = lane & 15, lg = lane >> 4;

    f32x4 acc[2][2];
    #pragma unroll
    for (int m=0;m<2;++m)
        #pragma unroll
        for (int n=0;n<2;++n)
            acc[m][n] = (f32x4){0.f,0.f,0.f,0.f};

    const __bf16* Ag = A + (long)m0*lda;
    const __bf16* Bg = Bm + (long)n0*ldb;
    const int NT = K >> 6;

    stageT<64>(Ag, lda, As[0], w, lane);   // 2 loads/thread
    stageT<64>(Bg, ldb, Bs[0], w, lane);   // 2 loads/thread
    int cur = 0;
    for (int t = 0; t < NT; ++t){
        if (t+1 < NT){
            stageT<64>(Ag + (t+1)*64, lda, As[cur^1], w, lane);
            stageT<64>(Bg + (t+1)*64, ldb, Bs[cur^1], w, lane);
            // wait for tile t's 4 loads (oldest); leave tile t+1's 4 in flight (T4)
            asm volatile("s_waitcnt vmcnt(4)" ::: "memory");
        } else {
            asm volatile("s_waitcnt vmcnt(0)" ::: "memory");
        }
        __builtin_amdgcn_sched_barrier(0);
        __builtin_amdgcn_s_barrier();          // tile t fully in LDS for all waves
        #pragma unroll
        for (int kk=0;kk<2;++kk){
            const int sa = ((kk*64 + lg*16) ^ ((lr&7)<<4));
            bf16x8 af[2], bfr[2];
            #pragma unroll
            for (int m=0;m<2;++m)
                af[m] = *(const bf16x8*)((const char*)&As[cur][0] + (wr*32 + m*16 + lr)*128 + sa);
            #pragma unroll
            for (int n=0;n<2;++n)
                bfr[n] = *(const bf16x8*)((const char*)&Bs[cur][0] + (wc*32 + n*16 + lr)*128 + sa);
            #pragma unroll
            for (int m=0;m<2;++m)
                #pragma unroll
                for (int n=0;n<2;++n)
                    acc[m][n] = __builtin_amdgcn_mfma_f32_16x16x32_bf16(af[m], bfr[n], acc[m][n], 0, 0, 0);
        }
        __builtin_amdgcn_s_barrier();          // all waves done reading buf[cur]
        cur ^= 1;
    }

    #pragma unroll
    for (int m=0;m<2;++m){
        #pragma unroll
        for (int n=0;n<2;++n){
            int col = n0 + wc*32 + n*16 + lr;
            if (col >= N) continue;
            #pragma unroll
            for (int e=0;e<4;++e){
                int row = m0 + wr*32 + m*16 + lg*4 + e;
                if (row >= M) continue;
                float v = acc[m][n][e]*scale;
                if (bias) v += bias[col];
                if (act) v = gelu_f(v);
                if (Rp) v += Rp[(long)bz*sR + (long)row*ldc + col];
                if (obf) ((__bf16*)Cp)[(long)bz*sC + (long)row*ldc + col] = (__bf16)v;
                else     ((float*)Cp)[(long)bz*sC + (long)row*ldc + col] = v;
            }
        }
    }
}

// ---------------- MFMA flash attention: block = (q-tile 64, head, batch), 4 waves ----------------
__global__ __launch_bounds__(256) void attn2(const __bf16* __restrict__ QKV, __bf16* __restrict__ O)
{
    __shared__ __align__(16) __bf16 Ks[64*64];
    __shared__ __align__(16) __bf16 VT[64*72];
    __shared__ __align__(16) __bf16 Ps[64*72];
    const int qt=blockIdx.x, h=blockIdx.y, b=blockIdx.z;
    const int tid=threadIdx.x, w=tid>>6, lane=tid&63;
    const int lr=lane&15, lg=lane>>4;
    const __bf16* base = QKV + (long)b*NTOK*1152;
    const long qrow = qt*64 + w*16 + lr;
    const bf16x8 qa0 = *(const bf16x8*)(base + qrow*1152 + h*64 + lg*8);
    const bf16x8 qa1 = *(const bf16x8*)(base + qrow*1152 + h*64 + 32 + lg*8);

    f32x4 oacc[4];
    float mo[4], lo[4];
    #pragma unroll
    for (int e=0;e<4;++e){ mo[e]=-1e30f; lo[e]=0.f; }
    #pragma unroll
    for (int n=0;n<4;++n) oacc[n]=(f32x4){0.f,0.f,0.f,0.f};

    for (int kt=0; kt<8; ++kt){
        __syncthreads();   // previous iteration's LDS readers done
        #pragma unroll
        for (int j=0;j<2;++j){
            int i = w*2+j;
            int ol = i*1024 + lane*16;
            int row = ol>>7, colb = ol&127;
            int sc = colb ^ ((row&7)<<4);
            gload16((const char*)base + ((long)(kt*64+row)*1152 + 384 + h*64)*2 + sc,
                    (char*)Ks + i*1024);
        }
        #pragma unroll
        for (int rep=0;rep<2;++rep){
            int c = tid + rep*256;
            int kv = c & 63, d8 = c >> 6;
            bf16x8 vv = *(const bf16x8*)(base + (long)(kt*64+kv)*1152 + 768 + h*64 + d8*8);
            #pragma unroll
            for (int jj=0;jj<8;++jj) VT[(d8*8+jj)*72 + kv] = vv[jj];
        }
        __syncthreads();   // staging visible

        f32x4 s[4];
        #pragma unroll
        for (int n=0;n<4;++n) s[n]=(f32x4){0.f,0.f,0.f,0.f};
        #pragma unroll
        for (int kk=0;kk<2;++kk){
            const int sa = ((kk*64 + lg*16) ^ ((lr&7)<<4));
            #pragma unroll
            for (int n=0;n<4;++n){
                bf16x8 kb = *(const bf16x8*)((const char*)Ks + (n*16+lr)*128 + sa);
                s[n] = __builtin_amdgcn_mfma_f32_16x16x32_bf16(kk? qa1:qa0, kb, s[n], 0,0,0);
            }
        }
        #pragma unroll
        for (int n=0;n<4;++n){
            int col = kt*64 + n*16 + lr;
            bool bad = col >= NTOK;
            #pragma unroll
            for (int e=0;e<4;++e) s[n][e] = bad ? -1e30f : s[n][e]*0.125f;
        }
        #pragma unroll
        for (int e=0;e<4;++e){
            float rm = fmaxf(fmaxf(s[0][e],s[1][e]), fmaxf(s[2][e],s[3][e]));
            rm = fmaxf(rm, __shfl_xor(rm,1));
            rm = fmaxf(rm, __shfl_xor(rm,2));
            rm = fmaxf(rm, __shfl_xor(rm,4));
            rm = fmaxf(rm, __shfl_xor(rm,8));
            float mn = fmaxf(mo[e], rm);
            float al = __expf(mo[e]-mn);
            float rs = 0.f;
            #pragma unroll
            for (int n=0;n<4;++n){ float p=__expf(s[n][e]-mn); s[n][e]=p; rs+=p; }
            rs += __shfl_xor(rs,1); rs += __shfl_xor(rs,2);
            rs += __shfl_xor(rs,4); rs += __shfl_xor(rs,8);
            lo[e] = lo[e]*al + rs; mo[e]=mn;
            #pragma unroll
            for (int n=0;n<4;++n) oacc[n][e] *= al;
        }
        #pragma unroll
        for (int n=0;n<4;++n)
            #pragma unroll
            for (int e=0;e<4;++e)
                Ps[(w*16+lg*4+e)*72 + n*16+lr] = (__bf16)s[n][e];
        #pragma unroll
        for (int kk=0;kk<2;++kk){
            bf16x8 pa = *(const bf16x8*)&Ps[(w*16+lr)*72 + kk*32 + lg*8];
            #pragma unroll
            for (int n=0;n<4;++n){
                bf16x8 vf = *(const bf16x8*)&VT[(n*16+lr)*72 + kk*32 + lg*8];
                oacc[n] = __builtin_amdgcn_mfma_f32_16x16x32_bf16(pa, vf, oacc[n], 0,0,0);
            }
        }
    }
    #pragma unroll
    for (int e=0;e<4;++e){
        int q = qt*64 + w*16 + lg*4 + e;
        if (q < NTOK){
            float inv = 1.f/lo[e];
            __bf16* op = O + ((long)b*NTOK + q)*TD + h*64;
            #pragma unroll
            for (int n=0;n<4;++n)
                op[n*16+lr] = (__bf16)(oacc[n][e]*inv);
        }
    }
}

// ---------------- LayerNorm row of 384 (fp32 in, bf16 out) ----------------
__global__ __launch_bounds__(128) void ln_kernel(const float* __restrict__ Xp, __bf16* __restrict__ Y,
    const float* __restrict__ W, const float* __restrict__ Bp)
{
    long r = blockIdx.x;
    int t = threadIdx.x;
    const float* x = Xp + r*TD;
    float v0 = x[t], v1 = x[t+128], v2 = x[t+256];
    float s = v0+v1+v2;
    float q = v0*v0+v1*v1+v2*v2;
    #pragma unroll
    for (int w=1; w<64; w<<=1){ s += __shfl_xor(s,w); q += __shfl_xor(q,w); }
    __shared__ float sm[2][2];
    if ((t&63)==0){ sm[t>>6][0]=s; sm[t>>6][1]=q; }
    __syncthreads();
    float S = sm[0][0]+sm[1][0];
    float Q = sm[0][1]+sm[1][1];
    float mean = S*(1.f/384.f);
    float var  = Q*(1.f/384.f) - mean*mean;
    float rstd = rsqrtf(var + 1e-6f);
    __bf16* y = Y + r*TD;
    y[t]     = (__bf16)((v0-mean)*rstd*W[t]     + Bp[t]);
    y[t+128] = (__bf16)((v1-mean)*rstd*W[t+128] + Bp[t+128]);
    y[t+256] = (__bf16)((v2-mean)*rstd*W[t+256] + Bp[t+256]);
}

// ---------------- weight fp32 -> bf16 ----------------
__global__ void wconv_kernel(const float* __restrict__ s, __bf16* __restrict__ d, int n4){
    int i = blockIdx.x*256 + threadIdx.x;
    if (i < n4){
        float4 v = ((const float4*)s)[i];
        bf16x4 p; p[0]=(__bf16)v.x; p[1]=(__bf16)v.y; p[2]=(__bf16)v.z; p[3]=(__bf16)v.w;
        ((bf16x4*)d)[i] = p;
    }
}

// ---------------- im2col (bf16 out) ----------------
__global__ void im2col_kernel(const float* __restrict__ in, __bf16* __restrict__ outp)
{
    long idx = (long)blockIdx.x*256 + threadIdx.x;
    if (idx >= (long)7680*1792) return;
    int k = (int)(idx % 1792);
    long m = idx / 1792;
    int pw = (int)(m % 40);
    long t2 = m / 40;
    int ph = (int)(t2 % 12);
    int b  = (int)(t2 / 12);
    int kw = k & 15, kh = (k >> 4) & 15, c = k >> 8;
    outp[idx] = (__bf16)in[(((long)(b*7 + c)*192) + ph*16 + kh)*640 + pw*16 + kw];
}

// ---------------- assemble x = [cls; conv_out] + pos (fp32) ----------------
__global__ void assemble_kernel(const float* __restrict__ CO, const float* __restrict__ cls,
    const float* __restrict__ pos, float* __restrict__ X)
{
    long idx = (long)blockIdx.x*256 + threadIdx.x;
    if (idx >= (long)NROWS*TD) return;
    int d = (int)(idx % TD);
    long r = idx / TD;
    int tok = (int)(r % NTOK);
    int b   = (int)(r / NTOK);
    float v = (tok == 0) ? cls[d] : CO[((long)b*480 + tok-1)*TD + d];
    X[idx] = v + pos[tok*TD + d];
}

// ---------------- pose maps ----------------
__global__ __launch_bounds__(256) void pose_maps_kernel(const float* __restrict__ PA,
    float* __restrict__ attn_map, float* __restrict__ masked_map)
{
    int i = blockIdx.x;   // 0..39
    int b = blockIdx.y;   // 0..15
    int t = threadIdx.x;
    float accA[12], accM[12];
    #pragma unroll
    for (int j=0;j<12;++j){ accA[j]=0.f; accM[j]=0.f; }
    for (int a = t; a < 480; a += 256) {
        const float* row = PA + ((long)(b*480 + a))*480 + i;
        float v[12];
        float mx = -1e30f;
        #pragma unroll
        for (int j=0;j<12;++j){ v[j] = row[40*j]; mx = fmaxf(mx, v[j]); }
        float sum = 0.f;
        #pragma unroll
        for (int j=0;j<12;++j){ v[j] = expf(v[j]-mx); sum += v[j]; }
        float invs = 1.f/sum;
        #pragma unroll
        for (int j=0;j<12;++j) v[j] *= invs;
        float srt[12];
        #pragma unroll
        for (int j=0;j<12;++j){
            float x = v[j]; int p = j;
            while (p > 0 && srt[p-1] > x){ srt[p]=srt[p-1]; --p; }
            srt[p]=x;
        }
        float med = srt[5];
        #pragma unroll
        for (int j=0;j<12;++j){
            accA[j] += v[j];
            accM[j] += (v[j] > med) ? 0.f : v[j];
        }
    }
    __shared__ float redA[256*12];
    __shared__ float redM[256*12];
    #pragma unroll
    for (int j=0;j<12;++j){ redA[t*12+j]=accA[j]; redM[t*12+j]=accM[j]; }
    __syncthreads();
    for (int sgap=128; sgap>0; sgap>>=1){
        if (t < sgap){
            #pragma unroll
            for (int j=0;j<12;++j){
                redA[t*12+j] += redA[(t+sgap)*12+j];
                redM[t*12+j] += redM[(t+sgap)*12+j];
            }
        }
        __syncthreads();
    }
    if (t < 12){
        attn_map  [(b*12 + t)*40 + i] = redA[t] * (1.f/480.f);
        masked_map[(b*12 + t)*40 + i] = redM[t] * (1.f/480.f) * (1.f/24.f);
    }
}

// ---------------- column-sum of pose V (bf16 in), 4-way row-split ----------------
__global__ __launch_bounds__(384) void colsum4_kernel(const __bf16* __restrict__ QKV2, float* __restrict__ CS4)
{
    int b = blockIdx.x, j = blockIdx.y, c = threadIdx.x;
    const __bf16* p = QKV2 + (long)b*480*1152 + 768 + c;
    float s = 0.f;
    for (int a = j*120; a < j*120+120; ++a) s += (float)p[(long)a*1152];
    CS4[((long)b*4 + j)*384 + c] = s;
}

// ---------------- final pose output: LN(40*colsum @ pose_w^T + pose_b) ----------------
__global__ __launch_bounds__(384) void pose_final_kernel(const float* __restrict__ CS4,
    const float* __restrict__ PW, const float* __restrict__ PB,
    const float* __restrict__ NW, const float* __restrict__ NBb, float* __restrict__ out)
{
    int b = blockIdx.x, c = threadIdx.x;
    const float* s0 = CS4 + (long)b*1536;
    __shared__ float sv[384];
    sv[c] = s0[c] + s0[384+c] + s0[768+c] + s0[1152+c];
    __syncthreads();
    const float* wr = PW + (long)c*384;
    float acc = 0.f;
    for (int k = 0; k < 384; ++k) acc += sv[k]*wr[k];
    acc = 40.f*acc + PB[c];
    float s = acc, q = acc*acc;
    #pragma unroll
    for (int w=1; w<64; w<<=1){ s += __shfl_xor(s,w); q += __shfl_xor(q,w); }
    __shared__ float sm[6][2];
    if ((c & 63) == 0){ sm[c>>6][0]=s; sm[c>>6][1]=q; }
    __syncthreads();
    float S=0.f, Q=0.f;
    for (int i=0;i<6;++i){ S+=sm[i][0]; Q+=sm[i][1]; }
    float mean = S*(1.f/384.f);
    float var  = Q*(1.f/384.f) - mean*mean;
    float rstd = rsqrtf(var + 1e-6f);
    out[b*384 + c] = (acc-mean)*rstd*NW[c] + NBb[c];
}

extern "C" void kernel_launch(void* const* d_in, const int* in_sizes, int n_in,
                              void* d_out, int out_size, void* d_ws, size_t ws_size,
                              hipStream_t stream)
{
    const float* input  = (const float*)d_in[0];
    const float* conv_w = (const float*)d_in[1];
    const float* conv_b = (const float*)d_in[2];
    const float* cls    = (const float*)d_in[3];
    const float* pos    = (const float*)d_in[4];
    const float* ln1w   = (const float*)d_in[5];
    const float* ln1b   = (const float*)d_in[6];
    const float* qkvw   = (const float*)d_in[7];
    const float* qkvb   = (const float*)d_in[8];
    const float* projw  = (const float*)d_in[9];
    const float* projb  = (const float*)d_in[10];
    const float* ln2w   = (const float*)d_in[11];
    const float* ln2b   = (const float*)d_in[12];
    const float* fc1w   = (const float*)d_in[13];
    const float* fc1b   = (const float*)d_in[14];
    const float* fc2w   = (const float*)d_in[15];
    const float* fc2b   = (const float*)d_in[16];
    const float* normw  = (const float*)d_in[17];
    const float* normb  = (const float*)d_in[18];
    const float* toqkvw = (const float*)d_in[19];
    const float* posew  = (const float*)d_in[20];
    const float* poseb  = (const float*)d_in[21];
    float* out = (float*)d_out;
    float* ws  = (float*)d_ws;

    // ---- workspace layout (float offsets); activation row-dim padded to 7808 ----
    __bf16* WB   = (__bf16*)ws;                    // weights bf16
    float*  X    = ws + 11182080;                  // 7696*384 fp32
    __bf16* Hbf  = (__bf16*)(ws + 14137344);       // 7808*384 bf16
    __bf16* QKVb = (__bf16*)(ws + 15636480);       // 7808*1536 bf16
    __bf16* Obuf = (__bf16*)(ws + 21633024);       // 7808*384 bf16
    float*  PAb  = ws + 23132160;                  // 16*480*480 fp32 (also conv tmp)
    float*  CS4  = PAb + 3686400;                  // 16*4*384 fp32
    __bf16* IM2C = QKVb;                           // alias spans QKVb+Obuf (pre-layer only)

    __bf16* Wconv = WB;
    __bf16* Wqkv  = WB + 688128;
    __bf16* Wproj = WB + 5996544;
    __bf16* Wfc1  = WB + 7766016;
    __bf16* Wfc2  = WB + 14843904;
    __bf16* Wtoq  = WB + 21921792;

    // ---- weights -> bf16 ----
    wconv_kernel<<<dim3((172032+255)/256), 256, 0, stream>>>(conv_w, Wconv, 172032);
    wconv_kernel<<<dim3((1327104+255)/256), 256, 0, stream>>>(qkvw,  Wqkv, 1327104);
    wconv_kernel<<<dim3((442368+255)/256), 256, 0, stream>>>(projw, Wproj, 442368);
    wconv_kernel<<<dim3((1769472+255)/256), 256, 0, stream>>>(fc1w,  Wfc1, 1769472);
    wconv_kernel<<<dim3((1769472+255)/256), 256, 0, stream>>>(fc2w,  Wfc2, 1769472);
    wconv_kernel<<<dim3((110592+255)/256), 256, 0, stream>>>(toqkvw, Wtoq, 110592);

    // ---- patch embed ----
    {
        long total = (long)7680*1792;
        im2col_kernel<<<dim3((unsigned)((total+255)/256)), 256, 0, stream>>>(input, IM2C);
    }
    mgemm<<<dim3(6, 120, 1), 256, 0, stream>>>(IM2C, 1792, 0, Wconv, 1792, 0,
        PAb, 384, 0, conv_b, nullptr, 0, 7680, 384, 1792, 1.f, 0, 0);
    assemble_kernel<<<dim3((NROWS*TD+255)/256), 256, 0, stream>>>(PAb, cls, pos, X);

    // ---- transformer layers ----
    for (int i = 0; i < 12; ++i) {
        ln_kernel<<<dim3(NROWS), 128, 0, stream>>>(X, Hbf, ln1w + i*384, ln1b + i*384);
        mgemm<<<dim3(18, 121, 1), 256, 0, stream>>>(Hbf, 384, 0, Wqkv + (long)i*1152*384, 384, 0,
            QKVb, 1152, 0, qkvb + i*1152, nullptr, 0, NROWS, 1152, 384, 1.f, 0, 1);
        attn2<<<dim3(8, NHEAD, NB), 256, 0, stream>>>(QKVb, Obuf);
        mgemm<<<dim3(6, 121, 1), 256, 0, stream>>>(Obuf, 384, 0, Wproj + (long)i*384*384, 384, 0,
            X, 384, 0, projb + i*384, X, 0, NROWS, 384, 384, 1.f, 0, 0);
        ln_kernel<<<dim3(NROWS), 128, 0, stream>>>(X, Hbf, ln2w + i*384, ln2b + i*384);
        mgemm<<<dim3(24, 121, 1), 256, 0, stream>>>(Hbf, 384, 0, Wfc1 + (long)i*1536*384, 384, 0,
            QKVb, 1536, 0, fc1b + i*1536, nullptr, 0, NROWS, 1536, 384, 1.f, 1, 1);
        mgemm<<<dim3(6, 121, 1), 256, 0, stream>>>(QKVb, 1536, 0, Wfc2 + (long)i*384*1536, 1536, 0,
            X, 384, 0, fc2b + i*384, X, 0, NROWS, 384, 1536, 1.f, 0, 0);
    }
    ln_kernel<<<dim3(NROWS), 128, 0, stream>>>(X, Hbf, normw, normb);

    // ---- pose head ----
    mgemm<<<dim3(18, 8, 16), 256, 0, stream>>>(Hbf + 384, 384, (long)481*384,
        Wtoq, 384, 0, QKVb, 1152, (long)480*1152, nullptr, nullptr, 0, 480, 1152, 384, 1.f, 0, 1);
    mgemm<<<dim3(8, 8, 16), 256, 0, stream>>>(QKVb, 1152, (long)480*1152,
        QKVb + 384, 1152, (long)480*1152, PAb, 480, (long)480*480, nullptr, nullptr, 0,
        480, 480, 384, 0.05103f*0.01f, 0, 0);
    pose_maps_kernel<<<dim3(40, 16), 256, 0, stream>>>(PAb, out + 6144, out + 13824);
    colsum4_kernel<<<dim3(16, 4), 384, 0, stream>>>(QKVb, CS4);
    pose_final_kernel<<<dim3(16), 384, 0, stream>>>(CS4, posew, poseb, normw, normb, out);
}